// Round 17
// baseline (280.934 us; speedup 1.0000x reference)
//
#include <hip/hip_runtime.h>
#include <math.h>

#define NSEQ  4096
#define DDIM  64
#define GH    64
#define NORMC 0.35355339059327373f   /* 64^-0.25 */
#define EPSC  1e-4f

typedef __bf16 bf16x8 __attribute__((ext_vector_type(8)));
typedef unsigned short u16x8 __attribute__((ext_vector_type(8)));
typedef unsigned short u16x4 __attribute__((ext_vector_type(4)));
typedef float f32x4 __attribute__((ext_vector_type(4)));

__device__ __forceinline__ unsigned enc_f(float f) {
    unsigned b = __float_as_uint(f);
    return (b & 0x80000000u) ? ~b : (b | 0x80000000u);
}
__device__ __forceinline__ float dec_f(unsigned u) {
    return (u & 0x80000000u) ? __uint_as_float(u & 0x7FFFFFFFu) : __uint_as_float(~u);
}
__device__ __forceinline__ void split_hl(float f, unsigned short& h, unsigned short& l) {
    unsigned u = __float_as_uint(f);
    unsigned hb = u & 0xffff0000u;
    h = (unsigned short)(hb >> 16);
    l = (unsigned short)(__float_as_uint(f - __uint_as_float(hb)) >> 16);
}
__device__ __forceinline__ unsigned short rne16(float f) {
    return (unsigned short)((__float_as_uint(f) + 0x8000u) >> 16);
}
__device__ __forceinline__ bf16x8 ldfrag(const unsigned short* p) {
    return __builtin_bit_cast(bf16x8, *(const u16x8*)p);
}
__device__ __forceinline__ f32x4 zero4() { f32x4 z = {0.f, 0.f, 0.f, 0.f}; return z; }
__device__ __forceinline__ f32x4 mfma3(bf16x8 ah, bf16x8 al, bf16x8 bh, bf16x8 bl, f32x4 c) {
    c = __builtin_amdgcn_mfma_f32_16x16x32_bf16(ah, bh, c, 0, 0, 0);
    c = __builtin_amdgcn_mfma_f32_16x16x32_bf16(ah, bl, c, 0, 0, 0);
    c = __builtin_amdgcn_mfma_f32_16x16x32_bf16(al, bh, c, 0, 0, 0);
    return c;
}
// opaque pass-through: defeats LICM/CSE on loads from p; emits no instructions
__device__ __forceinline__ const unsigned short* opaque(const unsigned short* p) {
    asm volatile("" : "+v"(p));
    return p;
}

// ======= Kernel P: pre-split NORMC*proj into bf16 hi/lo planes (64KB, L2-resident) =======
__global__ __launch_bounds__(256)
void kernP(const float* __restrict__ proj, unsigned short* __restrict__ Phi,
           unsigned short* __restrict__ Plo)
{
    const int m = threadIdx.x;
    for (int k = 0; k < 64; k += 4) {
        float4 p4 = *(const float4*)(proj + (size_t)m * 64 + k);
        float pe[4] = {p4.x, p4.y, p4.z, p4.w};
        u16x4 h4, l4;
#pragma unroll
        for (int j = 0; j < 4; j++) {
            unsigned short h, l;
            split_hl(NORMC * pe[j], h, l);
            h4[j] = h; l4[j] = l;
        }
        *(u16x4*)&Phi[m * 64 + k] = h4;
        *(u16x4*)&Plo[m * 64 + k] = l4;
    }
}

// ================= Kernel A: K-side, m-partitioned (MP=2), single-bf16 V, (256,2) =================
// (exact round-11/14 form — proven no-spill)
template<int NSLICE>
__global__ __launch_bounds__(256, 2)
void kernA(const float* __restrict__ kk, const float* __restrict__ vv,
           const float* __restrict__ proj, float* __restrict__ Apart,
           float* __restrict__ Aspart, float* __restrict__ Svpart,
           unsigned* __restrict__ mxk)
{
    const int slices = (NSLICE == 1) ? 16 : NSLICE;
    const int bx    = blockIdx.x;
    const int slice = bx & (slices - 1);
    const int mh    = bx / slices;          // 0/1 m-half
    const int g     = blockIdx.y;
    const int t     = threadIdx.x;
    const int lane  = t & 63;
    const int wq    = t >> 6;
    const int li    = lane & 15;
    const int lg    = lane >> 4;

    __shared__ __align__(16) unsigned short ARENA[12288];
    __shared__ float diag[2][32];
    __shared__ float svred[4][64];
    __shared__ float mxred[4];

    bf16x8 pfh[2][2], pfl[2][2];
#pragma unroll
    for (int u = 0; u < 2; u++)
#pragma unroll
    for (int s = 0; s < 2; s++) {
        const float* pr = proj + (size_t)(mh * 128 + wq * 32 + u * 16 + li) * DDIM + s * 32 + lg * 8;
        u16x8 hh, ll;
#pragma unroll
        for (int j = 0; j < 8; j++) {
            unsigned short h, l;
            split_hl(NORMC * pr[j], h, l);
            hh[j] = h; ll[j] = l;
        }
        pfh[u][s] = __builtin_bit_cast(bf16x8, hh);
        pfl[u][s] = __builtin_bit_cast(bf16x8, ll);
    }

    f32x4 cacc[4][2];
#pragma unroll
    for (int a = 0; a < 4; a++)
#pragma unroll
    for (int b = 0; b < 2; b++) cacc[a][b] = zero4();
    float as_loc[2] = {0.f, 0.f};
    float sv8[8] = {0.f,0.f,0.f,0.f,0.f,0.f,0.f,0.f};
    float mloc = -1e30f;

    const int stg_n = t >> 3;
    const int stg_c = t & 7;
    const int rows_per = NSEQ / slices;
    const int r_begin = slice * rows_per;
    const int vks = ((stg_n >> 2) & 3) * 8 + (stg_n >> 4) * 4 + (stg_n & 3);

    float4 ka0, ka1, va0, va1;
    auto load_tile = [&](int r0) {
        const float4* kb = (const float4*)(kk + ((size_t)g * NSEQ + r0 + stg_n) * DDIM + stg_c * 8);
        ka0 = kb[0]; ka1 = kb[1];
        const float4* vb = (const float4*)(vv + ((size_t)g * NSEQ + r0 + stg_n) * DDIM + stg_c * 8);
        va0 = vb[0]; va1 = vb[1];
    };
    auto stage_tile = [&](int b) {
        unsigned short* Khi  = ARENA + b * 6144;
        unsigned short* Klo  = Khi + 2048;
        unsigned short* Vthi = Khi + 4096;
        float ke[8] = {ka0.x,ka0.y,ka0.z,ka0.w,ka1.x,ka1.y,ka1.z,ka1.w};
        float sq = 0.f;
#pragma unroll
        for (int j = 0; j < 8; j++) sq += ke[j] * ke[j];
        sq += __shfl_xor(sq, 1); sq += __shfl_xor(sq, 2); sq += __shfl_xor(sq, 4);
        if (stg_c == 0) diag[b][stg_n] = 0.0625f * sq;
        u16x8 h8, l8;
#pragma unroll
        for (int j = 0; j < 8; j++) {
            unsigned short h, l;
            split_hl(ke[j], h, l);
            h8[j] = h; l8[j] = l;
        }
        int idx = stg_n * 64 + (stg_c ^ (stg_n & 7)) * 8;
        *(u16x8*)&Khi[idx] = h8;
        *(u16x8*)&Klo[idx] = l8;
        float ve[8] = {va0.x,va0.y,va0.z,va0.w,va1.x,va1.y,va1.z,va1.w};
#pragma unroll
        for (int j = 0; j < 8; j++) {
            sv8[j] += ve[j];
            int e = stg_c * 8 + j;
            int slot = vks ^ (((e >> 1) & 3) << 3);
            Vthi[e * 32 + slot] = rne16(ve[j]);
        }
    };

    load_tile(r_begin);
    stage_tile(0);
    __syncthreads();
    int cur = 0;
    const int NT = rows_per / 32;
    for (int it = 0; it < NT; ++it) {
        if (it + 1 < NT) load_tile(r_begin + (it + 1) * 32);
        const unsigned short* Khi  = ARENA + cur * 6144;
        const unsigned short* Klo  = Khi + 2048;
        const unsigned short* Vthi = Khi + 4096;
        f32x4 dacc[2][2];
#pragma unroll
        for (int tt = 0; tt < 2; tt++)
#pragma unroll
        for (int u = 0; u < 2; u++) dacc[tt][u] = zero4();
#pragma unroll
        for (int tt = 0; tt < 2; tt++)
#pragma unroll
        for (int s = 0; s < 2; s++) {
            int idx = (tt * 16 + li) * 64 + ((s * 4 + lg) ^ (li & 7)) * 8;
            bf16x8 ah = ldfrag(&Khi[idx]);
            bf16x8 al = ldfrag(&Klo[idx]);
#pragma unroll
            for (int u = 0; u < 2; u++) dacc[tt][u] = mfma3(ah, al, pfh[u][s], pfl[u][s], dacc[tt][u]);
        }
        u16x8 whh[2];
#pragma unroll
        for (int tt = 0; tt < 2; tt++)
#pragma unroll
        for (int u = 0; u < 2; u++)
#pragma unroll
        for (int r = 0; r < 4; r++) {
            float dash = dacc[tt][u][r];
            mloc = fmaxf(mloc, dash);
            float w = __expf(dash - diag[cur][tt * 16 + lg * 4 + r]);
            unsigned short hb = rne16(w);
            whh[u][tt * 4 + r] = hb;
            as_loc[u] += __uint_as_float((unsigned)hb << 16);
        }
        bf16x8 avh[4];
#pragma unroll
        for (int u2 = 0; u2 < 4; u2++) {
            int row = u2 * 16 + li;
            int slot = (lg ^ ((li >> 1) & 3)) * 8;
            avh[u2] = ldfrag(&Vthi[row * 32 + slot]);
        }
#pragma unroll
        for (int u = 0; u < 2; u++) {
            bf16x8 b = __builtin_bit_cast(bf16x8, whh[u]);
#pragma unroll
            for (int u2 = 0; u2 < 4; u2++)
                cacc[u2][u] = __builtin_amdgcn_mfma_f32_16x16x32_bf16(avh[u2], b, cacc[u2][u], 0, 0, 0);
        }
        if (it + 1 < NT) stage_tile(cur ^ 1);
        __syncthreads();
        cur ^= 1;
    }

#pragma unroll
    for (int j = 0; j < 8; j++) {
        float s = sv8[j];
        s += __shfl_xor(s, 8); s += __shfl_xor(s, 16); s += __shfl_xor(s, 32);
        sv8[j] = s;
    }
    if (lane < 8) {
#pragma unroll
        for (int j = 0; j < 8; j++) svred[wq][lane * 8 + j] = sv8[j];
    }
    float mm = mloc;
#pragma unroll
    for (int off = 32; off >= 1; off >>= 1) mm = fmaxf(mm, __shfl_xor(mm, off));
    if (lane == 0) mxred[wq] = mm;
#pragma unroll
    for (int u = 0; u < 2; u++) {
        float a = as_loc[u];
        a += __shfl_xor(a, 16); a += __shfl_xor(a, 32);
        as_loc[u] = a;
    }
    __syncthreads();
    if (t == 0) {
        float m4 = fmaxf(fmaxf(mxred[0], mxred[1]), fmaxf(mxred[2], mxred[3]));
        atomicMax(mxk + g, enc_f(m4));
    }
    if (t < 64 && mh == 0) {
        float s = svred[0][t] + svred[1][t] + svred[2][t] + svred[3][t];
        if (NSLICE == 1) atomicAdd(&Svpart[(size_t)g * 64 + t], s);
        else             Svpart[((size_t)g * NSLICE + slice) * 64 + t] = s;
    }
    if (lane < 16) {
#pragma unroll
        for (int u = 0; u < 2; u++) {
            int m = mh * 128 + wq * 32 + u * 16 + lane;
            if (NSLICE == 1) atomicAdd(&Aspart[(size_t)g * 256 + m], as_loc[u]);
            else             Aspart[((size_t)g * NSLICE + slice) * 256 + m] = as_loc[u];
        }
    }
    float* tb = (float*)ARENA + wq * 1024;
    float* Ad = (NSLICE == 1) ? (Apart + (size_t)g * 16384)
                              : (Apart + ((size_t)g * NSLICE + slice) * 16384);
    for (int u = 0; u < 2; u++) {
#pragma unroll
        for (int u2 = 0; u2 < 4; u2++)
#pragma unroll
        for (int r = 0; r < 4; r++)
            tb[li * 64 + ((((u2 << 2) | lg) ^ (li & 7)) << 2) + r] = cacc[u2][u][r];
#pragma unroll
        for (int j = 0; j < 4; j++) {
            int row16 = j * 4 + lg;
            int swz = li ^ (row16 & 7);
            f32x4 val = *(const f32x4*)&tb[row16 * 64 + swz * 4];
            float* dst = Ad + (mh * 128 + wq * 32 + u * 16) * 64 + j * 256 + lane * 4;
            if (NSLICE == 1) {
                atomicAdd(dst + 0, val[0]); atomicAdd(dst + 1, val[1]);
                atomicAdd(dst + 2, val[2]); atomicAdd(dst + 3, val[3]);
            } else {
                *(f32x4*)dst = val;
            }
        }
    }
}

// ================= Kernel B: reduce partials -> transposed single-bf16 ctx plane =================
__global__ __launch_bounds__(256)
void kernB(const float* __restrict__ Apart, const float* __restrict__ Aspart,
           const float* __restrict__ Svpart, const unsigned* __restrict__ mxk,
           unsigned short* __restrict__ ctxTh, float* __restrict__ ksum, int nslice)
{
    const int b = blockIdx.x;   // m-chunk of 16
    const int g = blockIdx.y;
    const int t = threadIdx.x;
    __shared__ float svh[64];
    __shared__ float TB[16][68];
    float emx = __expf(-dec_f(mxk[g]));
    if (t < 64) {
        float s = 0.f;
        for (int sb = 0; sb < nslice; sb++) s += Svpart[((size_t)g * nslice + sb) * 64 + t];
        svh[t] = s;
    }
    if (b == 0) {
        float as_s = 0.f;
        for (int sb = 0; sb < nslice; sb++) as_s += Aspart[((size_t)g * nslice + sb) * 256 + t];
        ksum[(size_t)g * 256 + t] = emx * as_s + EPSC * (float)NSEQ;
    }
    __syncthreads();
    const int mi = t >> 6, e = t & 63;
#pragma unroll
    for (int p = 0; p < 4; p++) {
        int ml = p * 4 + mi;
        int m  = b * 16 + ml;
        float s = 0.f;
        for (int sb = 0; sb < nslice; sb++)
            s += Apart[((size_t)g * nslice + sb) * 16384 + m * 64 + e];
        TB[ml][e] = emx * s + EPSC * svh[e];
    }
    __syncthreads();
    const int er = t >> 2, mj = (t & 3) * 4;
    u16x4 h4;
#pragma unroll
    for (int i = 0; i < 4; i++) h4[i] = rne16(TB[mj + i][er]);
    size_t base = (size_t)g * 16384 + (size_t)er * 256 + b * 16 + mj;
    *(u16x4*)&ctxTh[base] = h4;
}

// ====== Kernel C: Q-side; P/ctx frags phase-local via opaque pointers (defeat LICM) ======
__global__ __launch_bounds__(256, 2)
void kernC(const float* __restrict__ qq,
           const unsigned short* __restrict__ Phi, const unsigned short* __restrict__ Plo,
           const unsigned short* __restrict__ ctxTh,
           const float* __restrict__ ksum, float* __restrict__ outp)
{
    const int slice = blockIdx.x;   // 0..15
    const int g     = blockIdx.y;
    const int t     = threadIdx.x;
    const int lane  = t & 63;
    const int wq    = t >> 6;
    const int li    = lane & 15;
    const int lg    = lane >> 4;

    __shared__ __align__(16) unsigned short QAR[2][4096];  // per buf: Qhi | Qlo
    __shared__ __align__(16) unsigned short qph[8192];     // [n=32][m 256] bf16, granule-swizzled
    __shared__ float diag[2][32];
    __shared__ float rmax4[4][32];
    __shared__ float denp[4][32];

    float ksm[4];
#pragma unroll
    for (int u = 0; u < 4; u++) ksm[u] = ksum[(size_t)g * 256 + wq * 64 + u * 16 + li];

    // per-lane bases for phase-local fragment reloads (16B contiguous, L2-hot)
    const unsigned short* axbh = ctxTh + (size_t)g * 16384 + (size_t)(wq * 16 + li) * 256 + lg * 8;
    const unsigned short* pbh  = Phi + (size_t)(wq * 64 + li) * 64 + lg * 8;
    const unsigned short* pbl  = Plo + (size_t)(wq * 64 + li) * 64 + lg * 8;

    const int stg_n = t >> 3;
    const int stg_c = t & 7;
    const int r_begin = slice * (NSEQ / 16);

    float4 qa0, qa1;
    auto load_tile = [&](int r0) {
        const float4* qb = (const float4*)(qq + ((size_t)g * NSEQ + r0 + stg_n) * DDIM + stg_c * 8);
        qa0 = qb[0]; qa1 = qb[1];
    };
    auto stage_tile = [&](int b) {
        float qe[8] = {qa0.x,qa0.y,qa0.z,qa0.w,qa1.x,qa1.y,qa1.z,qa1.w};
        float sq = 0.f;
#pragma unroll
        for (int j = 0; j < 8; j++) sq += qe[j] * qe[j];
        sq += __shfl_xor(sq, 1); sq += __shfl_xor(sq, 2); sq += __shfl_xor(sq, 4);
        if (stg_c == 0) diag[b][stg_n] = 0.0625f * sq;
        u16x8 h8, l8;
#pragma unroll
        for (int j = 0; j < 8; j++) {
            unsigned short h, l;
            split_hl(qe[j], h, l);
            h8[j] = h; l8[j] = l;
        }
        int idx = stg_n * 64 + (stg_c ^ (stg_n & 7)) * 8;
        *(u16x8*)&QAR[b][idx] = h8;
        *(u16x8*)&QAR[b][2048 + idx] = l8;
    };

    load_tile(r_begin);
    stage_tile(0);
    __syncthreads();
    int cur = 0;
    for (int it = 0; it < 8; ++it) {
        if (it + 1 < 8) load_tile(r_begin + (it + 1) * 32);
        // fresh (opaque) bases each iteration -> loads stay in-loop, liveness phase-local
        const unsigned short* pbh_it = opaque(pbh);
        const unsigned short* pbl_it = opaque(pbl);
        // GEMM1: dash_q — Q frags from LDS, P frags phase-local from global (L2-hot)
        f32x4 dacc[2][4];
#pragma unroll
        for (int tt = 0; tt < 2; tt++)
#pragma unroll
        for (int u = 0; u < 4; u++) dacc[tt][u] = zero4();
#pragma unroll
        for (int s = 0; s < 2; s++) {
            bf16x8 qh_[2], ql_[2];
#pragma unroll
            for (int tt = 0; tt < 2; tt++) {
                int idx = (tt * 16 + li) * 64 + ((s * 4 + lg) ^ (li & 7)) * 8;
                qh_[tt] = ldfrag(&QAR[cur][idx]);
                ql_[tt] = ldfrag(&QAR[cur][2048 + idx]);
            }
#pragma unroll
            for (int u = 0; u < 4; u++) {
                bf16x8 bh = ldfrag(pbh_it + u * 1024 + s * 32);
                bf16x8 bl = ldfrag(pbl_it + u * 1024 + s * 32);
#pragma unroll
                for (int tt = 0; tt < 2; tt++)
                    dacc[tt][u] = mfma3(qh_[tt], ql_[tt], bh, bl, dacc[tt][u]);
            }
        }
        // row-max partials over this wave's m-quarter
#pragma unroll
        for (int tt = 0; tt < 2; tt++)
#pragma unroll
        for (int r = 0; r < 4; r++) {
            float v = fmaxf(fmaxf(dacc[tt][0][r], dacc[tt][1][r]),
                            fmaxf(dacc[tt][2][r], dacc[tt][3][r]));
            v = fmaxf(v, __shfl_xor(v, 1));
            v = fmaxf(v, __shfl_xor(v, 2));
            v = fmaxf(v, __shfl_xor(v, 4));
            v = fmaxf(v, __shfl_xor(v, 8));
            if (li == 0) rmax4[wq][tt * 16 + lg * 4 + r] = v;
        }
        __syncthreads();   // B
        // qp phase
        float dl[2][4] = {{0.f,0.f,0.f,0.f},{0.f,0.f,0.f,0.f}};
#pragma unroll
        for (int tt = 0; tt < 2; tt++) {
            float cb[4];
#pragma unroll
            for (int r = 0; r < 4; r++) {
                int n = tt * 16 + lg * 4 + r;
                cb[r] = diag[cur][n] + fmaxf(fmaxf(rmax4[0][n], rmax4[1][n]),
                                             fmaxf(rmax4[2][n], rmax4[3][n]));
            }
#pragma unroll
            for (int u = 0; u < 4; u++)
#pragma unroll
            for (int r = 0; r < 4; r++) {
                float qp = __expf(dacc[tt][u][r] - cb[r]) + EPSC;
                unsigned short hb = rne16(qp);
                dl[tt][r] += __uint_as_float((unsigned)hb << 16) * ksm[u];
                int n = tt * 16 + lg * 4 + r;
                int mg = wq * 64 + u * 16 + li;
                qph[n * 256 + (((mg >> 3) ^ (n & 7)) << 3) + (mg & 7)] = hb;
            }
        }
#pragma unroll
        for (int tt = 0; tt < 2; tt++)
#pragma unroll
        for (int r = 0; r < 4; r++) {
            float v = dl[tt][r];
            v += __shfl_xor(v, 1); v += __shfl_xor(v, 2);
            v += __shfl_xor(v, 4); v += __shfl_xor(v, 8);
            if (li == 0) denp[wq][tt * 16 + lg * 4 + r] = v;
        }
        if (it + 1 < 8) stage_tile(cur ^ 1);
        __syncthreads();   // C
        // phase-local ctx^T A-frags (opaque base -> stays in-loop)
        const unsigned short* axbh_it = opaque(axbh);
        bf16x8 axh[8];
#pragma unroll
        for (int mc = 0; mc < 8; mc++)
            axh[mc] = __builtin_bit_cast(bf16x8, *(const u16x8*)(axbh_it + mc * 32));
        // GEMM3 swapped: out^T[e][n] = ctx^T · qp^T  (16 mfmas)
        f32x4 oacc[2] = {zero4(), zero4()};
#pragma unroll
        for (int tt = 0; tt < 2; tt++) {
            int n = tt * 16 + li;
#pragma unroll
            for (int mc = 0; mc < 8; mc++) {
                bf16x8 b = ldfrag(&qph[n * 256 + (((mc * 4 + lg) ^ (li & 7)) << 3)]);
                oacc[tt] = __builtin_amdgcn_mfma_f32_16x16x32_bf16(axh[mc], b, oacc[tt], 0, 0, 0);
            }
        }
        // normalize + direct store
#pragma unroll
        for (int tt = 0; tt < 2; tt++) {
            int n = tt * 16 + li;
            float den = denp[0][n] + denp[1][n] + denp[2][n] + denp[3][n];
            float dinv = 1.0f / den;
            f32x4 o;
            o[0] = oacc[tt][0] * dinv; o[1] = oacc[tt][1] * dinv;
            o[2] = oacc[tt][2] * dinv; o[3] = oacc[tt][3] * dinv;
            float* op = outp + ((size_t)g * NSEQ + r_begin + it * 32 + n) * DDIM + wq * 16 + lg * 4;
            *(f32x4*)op = o;
        }
        cur ^= 1;
    }
}

extern "C" void kernel_launch(void* const* d_in, const int* in_sizes, int n_in,
                              void* d_out, int out_size, void* d_ws, size_t ws_size,
                              hipStream_t stream)
{
    const float* q    = (const float*)d_in[0];
    const float* k    = (const float*)d_in[1];
    const float* v    = (const float*)d_in[2];
    const float* proj = (const float*)d_in[3];
    float* outp = (float*)d_out;

    size_t per_ns = (size_t)GH * 16384 + (size_t)GH * 256 + (size_t)GH * 64;
    size_t fixed  = (size_t)GH * 16384 + (size_t)GH * 256;
    size_t need8  = 256 + 4 * (8 * per_ns + fixed);
    int ns = (ws_size >= need8) ? 8 : 1;

    unsigned* mxk = (unsigned*)d_ws;
    float* Apart  = (float*)((char*)d_ws + 256);
    float* Aspart = Apart  + (size_t)GH * ns * 16384;
    float* Svpart = Aspart + (size_t)GH * ns * 256;
    float* ctx    = Svpart + (size_t)GH * ns * 64;     // 4MB zone: ctxT hi plane (2MB) + P planes (64KB)
    float* ksum   = ctx    + (size_t)GH * 16384;

    unsigned short* ctxTh = (unsigned short*)ctx;
    unsigned short* Phi   = ctxTh + (size_t)GH * 16384;
    unsigned short* Plo   = Phi + 16384;

    kernP<<<1, 256, 0, stream>>>(proj, Phi, Plo);
    if (ns == 8) {
        hipMemsetAsync(d_ws, 0, 256, stream);
        kernA<8><<<dim3(16, GH), 256, 0, stream>>>(k, v, proj, Apart, Aspart, Svpart, mxk);
    } else {
        hipMemsetAsync(d_ws, 0, 256 + 4 * per_ns, stream);
        kernA<1><<<dim3(32, GH), 256, 0, stream>>>(k, v, proj, Apart, Aspart, Svpart, mxk);
    }
    kernB<<<dim3(16, GH), 256, 0, stream>>>(Apart, Aspart, Svpart, mxk, ctxTh, ksum, ns);
    kernC<<<dim3(16, GH), 256, 0, stream>>>(q, Phi, Plo, ctxTh, ksum, outp);
}

// Round 18
// 188.516 us; speedup vs baseline: 1.4902x; 1.4902x over previous
//
#include <hip/hip_runtime.h>
#include <math.h>

#define NSEQ  4096
#define DDIM  64
#define GH    64
#define NORMC 0.35355339059327373f   /* 64^-0.25 */
#define EPSC  1e-4f

typedef __bf16 bf16x8 __attribute__((ext_vector_type(8)));
typedef unsigned short u16x8 __attribute__((ext_vector_type(8)));
typedef unsigned short u16x4 __attribute__((ext_vector_type(4)));
typedef float f32x4 __attribute__((ext_vector_type(4)));

__device__ __forceinline__ unsigned enc_f(float f) {
    unsigned b = __float_as_uint(f);
    return (b & 0x80000000u) ? ~b : (b | 0x80000000u);
}
__device__ __forceinline__ float dec_f(unsigned u) {
    return (u & 0x80000000u) ? __uint_as_float(u & 0x7FFFFFFFu) : __uint_as_float(~u);
}
__device__ __forceinline__ void split_hl(float f, unsigned short& h, unsigned short& l) {
    unsigned u = __float_as_uint(f);
    unsigned hb = u & 0xffff0000u;
    h = (unsigned short)(hb >> 16);
    l = (unsigned short)(__float_as_uint(f - __uint_as_float(hb)) >> 16);
}
__device__ __forceinline__ unsigned short rne16(float f) {
    return (unsigned short)((__float_as_uint(f) + 0x8000u) >> 16);
}
__device__ __forceinline__ bf16x8 ldfrag(const unsigned short* p) {
    return __builtin_bit_cast(bf16x8, *(const u16x8*)p);
}
__device__ __forceinline__ f32x4 zero4() { f32x4 z = {0.f, 0.f, 0.f, 0.f}; return z; }
__device__ __forceinline__ f32x4 mfma3(bf16x8 ah, bf16x8 al, bf16x8 bh, bf16x8 bl, f32x4 c) {
    c = __builtin_amdgcn_mfma_f32_16x16x32_bf16(ah, bh, c, 0, 0, 0);
    c = __builtin_amdgcn_mfma_f32_16x16x32_bf16(ah, bl, c, 0, 0, 0);
    c = __builtin_amdgcn_mfma_f32_16x16x32_bf16(al, bh, c, 0, 0, 0);
    return c;
}

// ================= Kernel A: K-side, m-partitioned (MP=2), single-bf16 V, (256,2) =================
template<int NSLICE>
__global__ __launch_bounds__(256, 2)
void kernA(const float* __restrict__ kk, const float* __restrict__ vv,
           const float* __restrict__ proj, float* __restrict__ Apart,
           float* __restrict__ Aspart, float* __restrict__ Svpart,
           unsigned* __restrict__ mxk)
{
    const int slices = (NSLICE == 1) ? 16 : NSLICE;
    const int bx    = blockIdx.x;
    const int slice = bx & (slices - 1);
    const int mh    = bx / slices;          // 0/1 m-half
    const int g     = blockIdx.y;
    const int t     = threadIdx.x;
    const int lane  = t & 63;
    const int wq    = t >> 6;
    const int li    = lane & 15;
    const int lg    = lane >> 4;

    __shared__ __align__(16) unsigned short ARENA[12288];
    __shared__ float diag[2][32];
    __shared__ float svred[4][64];
    __shared__ float mxred[4];

    bf16x8 pfh[2][2], pfl[2][2];
#pragma unroll
    for (int u = 0; u < 2; u++)
#pragma unroll
    for (int s = 0; s < 2; s++) {
        const float* pr = proj + (size_t)(mh * 128 + wq * 32 + u * 16 + li) * DDIM + s * 32 + lg * 8;
        u16x8 hh, ll;
#pragma unroll
        for (int j = 0; j < 8; j++) {
            unsigned short h, l;
            split_hl(NORMC * pr[j], h, l);
            hh[j] = h; ll[j] = l;
        }
        pfh[u][s] = __builtin_bit_cast(bf16x8, hh);
        pfl[u][s] = __builtin_bit_cast(bf16x8, ll);
    }

    f32x4 cacc[4][2];
#pragma unroll
    for (int a = 0; a < 4; a++)
#pragma unroll
    for (int b = 0; b < 2; b++) cacc[a][b] = zero4();
    float as_loc[2] = {0.f, 0.f};
    float sv8[8] = {0.f,0.f,0.f,0.f,0.f,0.f,0.f,0.f};
    float mloc = -1e30f;

    const int stg_n = t >> 3;
    const int stg_c = t & 7;
    const int rows_per = NSEQ / slices;
    const int r_begin = slice * rows_per;
    const int vks = ((stg_n >> 2) & 3) * 8 + (stg_n >> 4) * 4 + (stg_n & 3);

    float4 ka0, ka1, va0, va1;
    auto load_tile = [&](int r0) {
        const float4* kb = (const float4*)(kk + ((size_t)g * NSEQ + r0 + stg_n) * DDIM + stg_c * 8);
        ka0 = kb[0]; ka1 = kb[1];
        const float4* vb = (const float4*)(vv + ((size_t)g * NSEQ + r0 + stg_n) * DDIM + stg_c * 8);
        va0 = vb[0]; va1 = vb[1];
    };
    auto stage_tile = [&](int b) {
        unsigned short* Khi  = ARENA + b * 6144;
        unsigned short* Klo  = Khi + 2048;
        unsigned short* Vthi = Khi + 4096;
        float ke[8] = {ka0.x,ka0.y,ka0.z,ka0.w,ka1.x,ka1.y,ka1.z,ka1.w};
        float sq = 0.f;
#pragma unroll
        for (int j = 0; j < 8; j++) sq += ke[j] * ke[j];
        sq += __shfl_xor(sq, 1); sq += __shfl_xor(sq, 2); sq += __shfl_xor(sq, 4);
        if (stg_c == 0) diag[b][stg_n] = 0.0625f * sq;
        u16x8 h8, l8;
#pragma unroll
        for (int j = 0; j < 8; j++) {
            unsigned short h, l;
            split_hl(ke[j], h, l);
            h8[j] = h; l8[j] = l;
        }
        int idx = stg_n * 64 + (stg_c ^ (stg_n & 7)) * 8;
        *(u16x8*)&Khi[idx] = h8;
        *(u16x8*)&Klo[idx] = l8;
        float ve[8] = {va0.x,va0.y,va0.z,va0.w,va1.x,va1.y,va1.z,va1.w};
#pragma unroll
        for (int j = 0; j < 8; j++) {
            sv8[j] += ve[j];
            int e = stg_c * 8 + j;
            int slot = vks ^ (((e >> 1) & 3) << 3);
            Vthi[e * 32 + slot] = rne16(ve[j]);
        }
    };

    load_tile(r_begin);
    stage_tile(0);
    __syncthreads();
    int cur = 0;
    const int NT = rows_per / 32;
    for (int it = 0; it < NT; ++it) {
        if (it + 1 < NT) load_tile(r_begin + (it + 1) * 32);
        const unsigned short* Khi  = ARENA + cur * 6144;
        const unsigned short* Klo  = Khi + 2048;
        const unsigned short* Vthi = Khi + 4096;
        f32x4 dacc[2][2];
#pragma unroll
        for (int tt = 0; tt < 2; tt++)
#pragma unroll
        for (int u = 0; u < 2; u++) dacc[tt][u] = zero4();
#pragma unroll
        for (int tt = 0; tt < 2; tt++)
#pragma unroll
        for (int s = 0; s < 2; s++) {
            int idx = (tt * 16 + li) * 64 + ((s * 4 + lg) ^ (li & 7)) * 8;
            bf16x8 ah = ldfrag(&Khi[idx]);
            bf16x8 al = ldfrag(&Klo[idx]);
#pragma unroll
            for (int u = 0; u < 2; u++) dacc[tt][u] = mfma3(ah, al, pfh[u][s], pfl[u][s], dacc[tt][u]);
        }
        u16x8 whh[2];
#pragma unroll
        for (int tt = 0; tt < 2; tt++)
#pragma unroll
        for (int u = 0; u < 2; u++)
#pragma unroll
        for (int r = 0; r < 4; r++) {
            float dash = dacc[tt][u][r];
            mloc = fmaxf(mloc, dash);
            float w = __expf(dash - diag[cur][tt * 16 + lg * 4 + r]);
            unsigned short hb = rne16(w);
            whh[u][tt * 4 + r] = hb;
            as_loc[u] += __uint_as_float((unsigned)hb << 16);
        }
        bf16x8 avh[4];
#pragma unroll
        for (int u2 = 0; u2 < 4; u2++) {
            int row = u2 * 16 + li;
            int slot = (lg ^ ((li >> 1) & 3)) * 8;
            avh[u2] = ldfrag(&Vthi[row * 32 + slot]);
        }
#pragma unroll
        for (int u = 0; u < 2; u++) {
            bf16x8 b = __builtin_bit_cast(bf16x8, whh[u]);
#pragma unroll
            for (int u2 = 0; u2 < 4; u2++)
                cacc[u2][u] = __builtin_amdgcn_mfma_f32_16x16x32_bf16(avh[u2], b, cacc[u2][u], 0, 0, 0);
        }
        if (it + 1 < NT) stage_tile(cur ^ 1);
        __syncthreads();
        cur ^= 1;
    }

#pragma unroll
    for (int j = 0; j < 8; j++) {
        float s = sv8[j];
        s += __shfl_xor(s, 8); s += __shfl_xor(s, 16); s += __shfl_xor(s, 32);
        sv8[j] = s;
    }
    if (lane < 8) {
#pragma unroll
        for (int j = 0; j < 8; j++) svred[wq][lane * 8 + j] = sv8[j];
    }
    float mm = mloc;
#pragma unroll
    for (int off = 32; off >= 1; off >>= 1) mm = fmaxf(mm, __shfl_xor(mm, off));
    if (lane == 0) mxred[wq] = mm;
#pragma unroll
    for (int u = 0; u < 2; u++) {
        float a = as_loc[u];
        a += __shfl_xor(a, 16); a += __shfl_xor(a, 32);
        as_loc[u] = a;
    }
    __syncthreads();
    if (t == 0) {
        float m4 = fmaxf(fmaxf(mxred[0], mxred[1]), fmaxf(mxred[2], mxred[3]));
        atomicMax(mxk + g, enc_f(m4));
    }
    if (t < 64 && mh == 0) {
        float s = svred[0][t] + svred[1][t] + svred[2][t] + svred[3][t];
        if (NSLICE == 1) atomicAdd(&Svpart[(size_t)g * 64 + t], s);
        else             Svpart[((size_t)g * NSLICE + slice) * 64 + t] = s;
    }
    if (lane < 16) {
#pragma unroll
        for (int u = 0; u < 2; u++) {
            int m = mh * 128 + wq * 32 + u * 16 + lane;
            if (NSLICE == 1) atomicAdd(&Aspart[(size_t)g * 256 + m], as_loc[u]);
            else             Aspart[((size_t)g * NSLICE + slice) * 256 + m] = as_loc[u];
        }
    }
    float* tb = (float*)ARENA + wq * 1024;
    float* Ad = (NSLICE == 1) ? (Apart + (size_t)g * 16384)
                              : (Apart + ((size_t)g * NSLICE + slice) * 16384);
    for (int u = 0; u < 2; u++) {
#pragma unroll
        for (int u2 = 0; u2 < 4; u2++)
#pragma unroll
        for (int r = 0; r < 4; r++)
            tb[li * 64 + ((((u2 << 2) | lg) ^ (li & 7)) << 2) + r] = cacc[u2][u][r];
#pragma unroll
        for (int j = 0; j < 4; j++) {
            int row16 = j * 4 + lg;
            int swz = li ^ (row16 & 7);
            f32x4 val = *(const f32x4*)&tb[row16 * 64 + swz * 4];
            float* dst = Ad + (mh * 128 + wq * 32 + u * 16) * 64 + j * 256 + lane * 4;
            if (NSLICE == 1) {
                atomicAdd(dst + 0, val[0]); atomicAdd(dst + 1, val[1]);
                atomicAdd(dst + 2, val[2]); atomicAdd(dst + 3, val[3]);
            } else {
                *(f32x4*)dst = val;
            }
        }
    }
}

// ================= Kernel B: reduce partials -> transposed single-bf16 ctx plane =================
__global__ __launch_bounds__(256)
void kernB(const float* __restrict__ Apart, const float* __restrict__ Aspart,
           const float* __restrict__ Svpart, const unsigned* __restrict__ mxk,
           unsigned short* __restrict__ ctxTh, float* __restrict__ ksum, int nslice)
{
    const int b = blockIdx.x;   // m-chunk of 16
    const int g = blockIdx.y;
    const int t = threadIdx.x;
    __shared__ float svh[64];
    __shared__ float TB[16][68];
    float emx = __expf(-dec_f(mxk[g]));
    if (t < 64) {
        float s = 0.f;
        for (int sb = 0; sb < nslice; sb++) s += Svpart[((size_t)g * nslice + sb) * 64 + t];
        svh[t] = s;
    }
    if (b == 0) {
        float as_s = 0.f;
        for (int sb = 0; sb < nslice; sb++) as_s += Aspart[((size_t)g * nslice + sb) * 256 + t];
        ksum[(size_t)g * 256 + t] = emx * as_s + EPSC * (float)NSEQ;
    }
    __syncthreads();
    const int mi = t >> 6, e = t & 63;
#pragma unroll
    for (int p = 0; p < 4; p++) {
        int ml = p * 4 + mi;
        int m  = b * 16 + ml;
        float s = 0.f;
        for (int sb = 0; sb < nslice; sb++)
            s += Apart[((size_t)g * nslice + sb) * 16384 + m * 64 + e];
        TB[ml][e] = emx * s + EPSC * svh[e];
    }
    __syncthreads();
    const int er = t >> 2, mj = (t & 3) * 4;
    u16x4 h4;
#pragma unroll
    for (int i = 0; i < 4; i++) h4[i] = rne16(TB[mj + i][er]);
    size_t base = (size_t)g * 16384 + (size_t)er * 256 + b * 16 + mj;
    *(u16x4*)&ctxTh[base] = h4;
}

// ================= Kernel C: Q-side, single-bf16 ctx GEMM3, (256,2), 32-row tiles =================
__global__ __launch_bounds__(256, 2)
void kernC(const float* __restrict__ qq, const float* __restrict__ proj,
           const unsigned short* __restrict__ ctxTh,
           const float* __restrict__ ksum, float* __restrict__ outp)
{
    const int slice = blockIdx.x;   // 0..15
    const int g     = blockIdx.y;
    const int t     = threadIdx.x;
    const int lane  = t & 63;
    const int wq    = t >> 6;
    const int li    = lane & 15;
    const int lg    = lane >> 4;

    __shared__ __align__(16) unsigned short QAR[2][4096];  // per buf: Qhi | Qlo
    __shared__ __align__(16) unsigned short qph[8192];     // [n=32][m 256] bf16, granule-swizzled
    __shared__ float diag[2][32];
    __shared__ float rmax4[4][32];
    __shared__ float denp[4][32];

    bf16x8 pfh[4][2], pfl[4][2];
#pragma unroll
    for (int u = 0; u < 4; u++)
#pragma unroll
    for (int s = 0; s < 2; s++) {
        const float* pr = proj + (size_t)(wq * 64 + u * 16 + li) * DDIM + s * 32 + lg * 8;
        u16x8 hh, ll;
#pragma unroll
        for (int j = 0; j < 8; j++) {
            unsigned short h, l;
            split_hl(NORMC * pr[j], h, l);
            hh[j] = h; ll[j] = l;
        }
        pfh[u][s] = __builtin_bit_cast(bf16x8, hh);
        pfl[u][s] = __builtin_bit_cast(bf16x8, ll);
    }
    float ksm[4];
#pragma unroll
    for (int u = 0; u < 4; u++) ksm[u] = ksum[(size_t)g * 256 + wq * 64 + u * 16 + li];

    const unsigned short* axbh = ctxTh + (size_t)g * 16384 + (size_t)(wq * 16 + li) * 256 + lg * 8;

    const int stg_n = t >> 3;
    const int stg_c = t & 7;
    const int r_begin = slice * (NSEQ / 16);

    float4 qa0, qa1;
    auto load_tile = [&](int r0) {
        const float4* qb = (const float4*)(qq + ((size_t)g * NSEQ + r0 + stg_n) * DDIM + stg_c * 8);
        qa0 = qb[0]; qa1 = qb[1];
    };
    auto stage_tile = [&](int b) {
        float qe[8] = {qa0.x,qa0.y,qa0.z,qa0.w,qa1.x,qa1.y,qa1.z,qa1.w};
        float sq = 0.f;
#pragma unroll
        for (int j = 0; j < 8; j++) sq += qe[j] * qe[j];
        sq += __shfl_xor(sq, 1); sq += __shfl_xor(sq, 2); sq += __shfl_xor(sq, 4);
        if (stg_c == 0) diag[b][stg_n] = 0.0625f * sq;
        u16x8 h8, l8;
#pragma unroll
        for (int j = 0; j < 8; j++) {
            unsigned short h, l;
            split_hl(qe[j], h, l);
            h8[j] = h; l8[j] = l;
        }
        int idx = stg_n * 64 + (stg_c ^ (stg_n & 7)) * 8;
        *(u16x8*)&QAR[b][idx] = h8;
        *(u16x8*)&QAR[b][2048 + idx] = l8;
    };

    load_tile(r_begin);
    stage_tile(0);
    __syncthreads();
    int cur = 0;
    for (int it = 0; it < 8; ++it) {
        if (it + 1 < 8) load_tile(r_begin + (it + 1) * 32);
        // GEMM1: dash_q
        f32x4 dacc[2][4];
#pragma unroll
        for (int tt = 0; tt < 2; tt++)
#pragma unroll
        for (int u = 0; u < 4; u++) dacc[tt][u] = zero4();
#pragma unroll
        for (int tt = 0; tt < 2; tt++)
#pragma unroll
        for (int s = 0; s < 2; s++) {
            int idx = (tt * 16 + li) * 64 + ((s * 4 + lg) ^ (li & 7)) * 8;
            bf16x8 ah = ldfrag(&QAR[cur][idx]);
            bf16x8 al = ldfrag(&QAR[cur][2048 + idx]);
#pragma unroll
            for (int u = 0; u < 4; u++) dacc[tt][u] = mfma3(ah, al, pfh[u][s], pfl[u][s], dacc[tt][u]);
        }
        // row-max partials over this wave's m-quarter
#pragma unroll
        for (int tt = 0; tt < 2; tt++)
#pragma unroll
        for (int r = 0; r < 4; r++) {
            float v = fmaxf(fmaxf(dacc[tt][0][r], dacc[tt][1][r]),
                            fmaxf(dacc[tt][2][r], dacc[tt][3][r]));
            v = fmaxf(v, __shfl_xor(v, 1));
            v = fmaxf(v, __shfl_xor(v, 2));
            v = fmaxf(v, __shfl_xor(v, 4));
            v = fmaxf(v, __shfl_xor(v, 8));
            if (li == 0) rmax4[wq][tt * 16 + lg * 4 + r] = v;
        }
        __syncthreads();   // B
        // qp phase
        float dl[2][4] = {{0.f,0.f,0.f,0.f},{0.f,0.f,0.f,0.f}};
#pragma unroll
        for (int tt = 0; tt < 2; tt++) {
            float cb[4];
#pragma unroll
            for (int r = 0; r < 4; r++) {
                int n = tt * 16 + lg * 4 + r;
                cb[r] = diag[cur][n] + fmaxf(fmaxf(rmax4[0][n], rmax4[1][n]),
                                             fmaxf(rmax4[2][n], rmax4[3][n]));
            }
#pragma unroll
            for (int u = 0; u < 4; u++)
#pragma unroll
            for (int r = 0; r < 4; r++) {
                float qp = __expf(dacc[tt][u][r] - cb[r]) + EPSC;
                unsigned short hb = rne16(qp);
                dl[tt][r] += __uint_as_float((unsigned)hb << 16) * ksm[u];
                int n = tt * 16 + lg * 4 + r;
                int mg = wq * 64 + u * 16 + li;
                qph[n * 256 + (((mg >> 3) ^ (n & 7)) << 3) + (mg & 7)] = hb;
            }
        }
#pragma unroll
        for (int tt = 0; tt < 2; tt++)
#pragma unroll
        for (int r = 0; r < 4; r++) {
            float v = dl[tt][r];
            v += __shfl_xor(v, 1); v += __shfl_xor(v, 2);
            v += __shfl_xor(v, 4); v += __shfl_xor(v, 8);
            if (li == 0) denp[wq][tt * 16 + lg * 4 + r] = v;
        }
        if (it + 1 < 8) stage_tile(cur ^ 1);
        __syncthreads();   // C
        // phase-local ctx^T A-frags (single plane, L2-hot)
        bf16x8 axh[8];
#pragma unroll
        for (int mc = 0; mc < 8; mc++)
            axh[mc] = __builtin_bit_cast(bf16x8, *(const u16x8*)(axbh + mc * 32));
        // GEMM3 swapped: out^T[e][n] = ctx^T · qp^T  (16 mfmas)
        f32x4 oacc[2] = {zero4(), zero4()};
#pragma unroll
        for (int tt = 0; tt < 2; tt++) {
            int n = tt * 16 + li;
#pragma unroll
            for (int mc = 0; mc < 8; mc++) {
                bf16x8 b = ldfrag(&qph[n * 256 + (((mc * 4 + lg) ^ (li & 7)) << 3)]);
                oacc[tt] = __builtin_amdgcn_mfma_f32_16x16x32_bf16(axh[mc], b, oacc[tt], 0, 0, 0);
            }
        }
        // normalize + direct store
#pragma unroll
        for (int tt = 0; tt < 2; tt++) {
            int n = tt * 16 + li;
            float den = denp[0][n] + denp[1][n] + denp[2][n] + denp[3][n];
            float dinv = 1.0f / den;
            f32x4 o;
            o[0] = oacc[tt][0] * dinv; o[1] = oacc[tt][1] * dinv;
            o[2] = oacc[tt][2] * dinv; o[3] = oacc[tt][3] * dinv;
            float* op = outp + ((size_t)g * NSEQ + r_begin + it * 32 + n) * DDIM + wq * 16 + lg * 4;
            *(f32x4*)op = o;
        }
        cur ^= 1;
    }
}

extern "C" void kernel_launch(void* const* d_in, const int* in_sizes, int n_in,
                              void* d_out, int out_size, void* d_ws, size_t ws_size,
                              hipStream_t stream)
{
    const float* q    = (const float*)d_in[0];
    const float* k    = (const float*)d_in[1];
    const float* v    = (const float*)d_in[2];
    const float* proj = (const float*)d_in[3];
    float* outp = (float*)d_out;

    size_t per_ns = (size_t)GH * 16384 + (size_t)GH * 256 + (size_t)GH * 64;
    size_t fixed  = (size_t)GH * 16384 + (size_t)GH * 256;
    size_t need8  = 256 + 4 * (8 * per_ns + fixed);
    int ns = (ws_size >= need8) ? 8 : 1;

    unsigned* mxk = (unsigned*)d_ws;
    float* Apart  = (float*)((char*)d_ws + 256);
    float* Aspart = Apart  + (size_t)GH * ns * 16384;
    float* Svpart = Aspart + (size_t)GH * ns * 256;
    float* ctx    = Svpart + (size_t)GH * ns * 64;     // reused as ctxT hi plane
    float* ksum   = ctx    + (size_t)GH * 16384;

    unsigned short* ctxTh = (unsigned short*)ctx;

    if (ns == 8) {
        hipMemsetAsync(d_ws, 0, 256, stream);
        kernA<8><<<dim3(16, GH), 256, 0, stream>>>(k, v, proj, Apart, Aspart, Svpart, mxk);
    } else {
        hipMemsetAsync(d_ws, 0, 256 + 4 * per_ns, stream);
        kernA<1><<<dim3(32, GH), 256, 0, stream>>>(k, v, proj, Apart, Aspart, Svpart, mxk);
    }
    kernB<<<dim3(16, GH), 256, 0, stream>>>(Apart, Aspart, Svpart, mxk, ctxTh, ksum, ns);
    kernC<<<dim3(16, GH), 256, 0, stream>>>(q, proj, ctxTh, ksum, outp);
}